// Round 5
// baseline (225.454 us; speedup 1.0000x reference)
//
#include <hip/hip_runtime.h>
#include <hip/hip_bf16.h>
#include <math.h>

// Problem constants (GenNeuronStates): B=2,G=4,N=1024,H=16,dq=dv=64
#define B_ 2
#define G_ 4
#define N_ 1024
#define H_ 16
#define D_ 64
#define BG_ (B_*G_)
#define BGH_ (B_*G_*H_)
#define MK 64   // K/V tile rows per flash iteration
#define LOG2E 1.44269504f
#define QSCALE (0.125f * LOG2E)   // folded into Q during transpose

typedef __bf16 bf16;
typedef bf16 bf16x8 __attribute__((ext_vector_type(8)));
typedef bf16 bf16x2 __attribute__((ext_vector_type(2)));
typedef float f32x4 __attribute__((ext_vector_type(4)));
typedef float f32x16 __attribute__((ext_vector_type(16)));
typedef int i32x4 __attribute__((ext_vector_type(4)));
typedef unsigned u32x2 __attribute__((ext_vector_type(2)));

static __device__ __forceinline__ f32x16 mfma32(bf16x8 a, bf16x8 b, f32x16 c) {
    return __builtin_amdgcn_mfma_f32_32x32x16_bf16(a, b, c, 0, 0, 0);
}

// pack two f32 -> one dword of 2 bf16 (compiler emits v_cvt_pk_bf16_f32)
static __device__ __forceinline__ unsigned pk2(float a, float b) {
    bf16x2 t; t[0] = (bf16)a; t[1] = (bf16)b;
    return __builtin_bit_cast(unsigned, t);
}

// permlane32_swap: a' = {a.lo, b.lo}, b' = {a.hi, b.hi}  (halves = lanes 0-31 / 32-63)
static __device__ __forceinline__ void pl32swap(unsigned& a, unsigned& b, int hi) {
#if __has_builtin(__builtin_amdgcn_permlane32_swap)
    u32x2 r = __builtin_amdgcn_permlane32_swap(a, b, false, false);
    a = r[0]; b = r[1];
    (void)hi;
#else
    unsigned ax = (unsigned)__shfl_xor((int)a, 32, 64);
    unsigned bx = (unsigned)__shfl_xor((int)b, 32, 64);
    unsigned na = hi ? bx : a;
    unsigned nb = hi ? b : ax;
    a = na; b = nb;
#endif
}

// async global->LDS, 16B per lane; dest = wave-uniform base + lane*16 (m104)
static __device__ __forceinline__ void gll16(const void* gsrc, void* ldst, int lane) {
#if __has_builtin(__builtin_amdgcn_global_load_lds)
    (void)lane;
    __builtin_amdgcn_global_load_lds((const __attribute__((address_space(1))) void*)gsrc,
                                     (__attribute__((address_space(3))) void*)ldst, 16, 0, 0);
#else
    *(bf16x8*)((bf16*)ldst + lane * 8) = *(const bf16x8*)((const bf16*)gsrc);
#endif
}

// ---------------------------------------------------------------------------
// Fused prep pass.
//   bx < 1536 : Q/K/V transpose (V writes 16-chunked vtT16[bgh][n/16][d][16])
//   bx >= 1536: bias blocked-transpose biasX[g][m/4][q][4] (f32x4-granular)
// ---------------------------------------------------------------------------
#define HS 1160
#define NS 72

__global__ __launch_bounds__(256) void transpose_fused(
    const float* __restrict__ q, const float* __restrict__ k, const float* __restrict__ v,
    const float* __restrict__ bias,
    bf16* __restrict__ qt, bf16* __restrict__ ktb, bf16* __restrict__ vtT16,
    float* __restrict__ biasX)
{
    __shared__ __attribute__((aligned(16))) bf16 lds[16 * HS];  // 37.1 KB (reused by bias branch)
    int bx = blockIdx.x;
    int t = threadIdx.x;

    if (bx >= 3 * 512) {
        // ---- bias blocked transpose: biasX[((g*256+mb)*1024+q)*4+mo] = bias[g][q][4mb+mo]
        int idx = bx - 3 * 512;
        int gg  = idx >> 8;            // 0..3
        int tl  = idx & 255;
        int q0  = (tl >> 4) * 64;
        int m0  = (tl & 15) * 64;
        float* ldsF = (float*)lds;     // [64][68] f32, 17.4 KB

        int mi = t & 15, qr = t >> 4;
#pragma unroll
        for (int rr = 0; rr < 4; ++rr) {
            int row = qr + rr * 16;
            f32x4 val = *(const f32x4*)(bias + ((size_t)(gg * N_ + q0 + row) * N_ + m0 + 4 * mi));
            *(f32x4*)(&ldsF[row * 68 + 4 * mi]) = val;
        }
        __syncthreads();
        int qr2 = t & 63, mb0 = t >> 6;
#pragma unroll
        for (int kk = 0; kk < 4; ++kk) {
            int mbi = mb0 + kk * 4;    // 0..15
            f32x4 vv = *(const f32x4*)(&ldsF[qr2 * 68 + 4 * mbi]);
            *(f32x4*)(biasX + (((size_t)gg * 256 + m0 / 4 + mbi) * N_ + q0 + qr2) * 4) = vv;
        }
        return;
    }

    int tensor = bx >> 9;          // 512 blocks per tensor
    int rr = bx & 511;
    int bg = rr >> 6;
    int tile = rr & 63;
    int n0 = tile * 16;

    const float* src = (tensor == 0) ? q : (tensor == 1) ? k : v;
    float scale = (tensor == 0) ? QSCALE : 1.0f;
    const float* sb = src + (size_t)bg * N_ * 1024 + (size_t)n0 * 1024;

    int h0 = 4 * (t & 3);          // element j of the float4 has h = h0+j, same d
    int d  = t >> 2;
    int wbase = h0 * HS + d;
#pragma unroll 4
    for (int i = 0; i < 16; ++i) {
        float4 val = ((const float4*)(sb + (size_t)i * 1024))[t];
        bf16* p = &lds[wbase + i * NS];
        p[0]        = (bf16)(val.x * scale);
        p[HS]       = (bf16)(val.y * scale);
        p[2 * HS]   = (bf16)(val.z * scale);
        p[3 * HS]   = (bf16)(val.w * scale);
    }
    __syncthreads();

    if (tensor < 2) {
        bf16* dst = (tensor == 0) ? qt : ktb;
        int n  = (t >> 3) & 15;
        int db = t & 7;
        int hb = t >> 7;
#pragma unroll
        for (int i = 0; i < 8; ++i) {
            int h = 2 * i + hb;
            bf16x8 vv = *(const bf16x8*)(&lds[h * HS + n * NS + db * 8]);
            *(bf16x8*)(dst + (((size_t)(bg * H_ + h)) * N_ + n0 + n) * D_ + db * 8) = vv;
        }
    } else {
        // V -> vtT16[bgh][nchunk=tile][d][16]; lanes at consecutive d -> 2KB runs
        int dd = t & 63;
        int hb = t >> 6;           // 0..3
#pragma unroll
        for (int i = 0; i < 4; ++i) {
            int h = hb * 4 + i;
            bf16x8 v0, v1;
#pragma unroll
            for (int jj = 0; jj < 8; ++jj) v0[jj] = lds[h * HS + jj * NS + dd];
#pragma unroll
            for (int jj = 0; jj < 8; ++jj) v1[jj] = lds[h * HS + (8 + jj) * NS + dd];
            bf16* dst = vtT16 + (((size_t)(bg * H_ + h) * 64 + tile) * D_ + dd) * 16;
            *(bf16x8*)dst       = v0;
            *(bf16x8*)(dst + 8) = v1;
        }
    }
}

// ---------------------------------------------------------------------------
// Flash v10 = v9 + 2x LDS-read reuse: each wave owns 64 q-cols (2 groups of
// 32); every K/V b128 fragment read feeds MFMAs for BOTH groups (16 reads ->
// 32 MFMAs/wave-iter, was 16->16). The 64-row K-tile is processed as two
// 32-row halves end-to-end (QK->exp->PV per half; no row-max so this is
// exact), keeping only one 32-row S pair live (32 VGPR). Block = 256 q-rows,
// grid 512 (2 blocks/CU, all co-resident). Bias per-half double-buffered in
// regs. XCD swizzle: xcd=wg&7 owns one (b,g) -> K/V/bias L2-resident.
// ---------------------------------------------------------------------------
__global__ __launch_bounds__(256, 2) void flash_kernel(
    const bf16* __restrict__ qt, const bf16* __restrict__ kt, const bf16* __restrict__ vtT16,
    const float* __restrict__ biasX, float* __restrict__ out)
{
    __shared__ __attribute__((aligned(16))) bf16 k_lds[2][MK][D_];  // [buf][m][d] linear
    __shared__ __attribute__((aligned(16))) bf16 v_lds[2][D_][MK];  // [buf][d][m] linear

    int tid  = threadIdx.x;
    int w    = tid >> 6;
    int lane = tid & 63;
    int hi   = lane >> 5;
    int q31  = lane & 31;
    int key8 = (q31 & 7) << 3;     // elem-XOR key for frag reads (8-elem granule)
    int hi8  = hi << 3;

    // XCD-bijective swizzle: 512 blocks; each XCD owns one (b,g) = 16 bgh x 4 qtiles
    int wg   = blockIdx.x;
    int xcd  = wg & 7;
    int slot = wg >> 3;            // 0..63
    int bgh  = xcd * 16 + (slot >> 2);
    int n0   = (slot & 3) * 256;
    int g    = (bgh >> 4) & (G_ - 1);   // bgh = (b*G+g)*H + h

    int qbase = n0 + w * 64;

    // Q B-frags, both groups (loop-invariant): 8 x bf16x8 = 32 VGPR
    const bf16* qb_base = qt + ((size_t)bgh * N_ + qbase + q31) * D_ + hi * 8;
    bf16x8 qA[4], qB[4];
#pragma unroll
    for (int c = 0; c < 4; ++c) {
        qA[c] = *(const bf16x8*)(qb_base + c * 16);
        qB[c] = *(const bf16x8*)(qb_base + 32 * D_ + c * 16);
    }

    f32x16 acc00 = {0,0,0,0,0,0,0,0,0,0,0,0,0,0,0,0};  // g0, d 0-31
    f32x16 acc01 = {0,0,0,0,0,0,0,0,0,0,0,0,0,0,0,0};  // g0, d 32-63
    f32x16 acc10 = {0,0,0,0,0,0,0,0,0,0,0,0,0,0,0,0};  // g1, d 0-31
    f32x16 acc11 = {0,0,0,0,0,0,0,0,0,0,0,0,0,0,0,0};  // g1, d 32-63
    float l0 = 0.f, l1 = 0.f;

    // ---- staging geometry: waves 0,1 stage K rows wrow..wrow+31; waves 2,3 stage V
    int rloc = lane >> 3;              // 0..7
    int c16  = lane & 7;               // 16B chunk within 128B row
    int csw  = c16 ^ rloc;             // source chunk (row&7 == rloc for all instrs)
    bool isK = (w < 2);
    int wrow = (w & 1) * 32;
    const bf16* ksrc = kt + (size_t)bgh * N_ * D_ + (size_t)(wrow + rloc) * D_ + csw * 8;
    const bf16* vsrc = vtT16 + (((size_t)bgh * 64 + (csw >> 1)) * D_ + (wrow + rloc)) * 16 + (csw & 1) * 8;

    // ---- bias: lane's q-col in biasX; quad (mb) at mb*4096 floats; group1 at +128
    const float* bb = biasX + (size_t)g * (256u * 4096) + (size_t)(qbase + q31) * 4;

    // ---- prologue: stage tile 0 + bias tiles (half A and half B of iter 0) ----
    if (isK) {
#pragma unroll
        for (int i = 0; i < 4; ++i) gll16(ksrc + (size_t)i * 8 * D_, &k_lds[0][wrow + i * 8][0], lane);
    } else {
#pragma unroll
        for (int i = 0; i < 4; ++i) gll16(vsrc + (size_t)i * 128, &v_lds[0][wrow + i * 8][0], lane);
    }
    f32x4 bvA[2][4], bvB[2][4];
#pragma unroll
    for (int g01 = 0; g01 < 2; ++g01)
#pragma unroll
        for (int u = 0; u < 4; ++u) {
            bvA[g01][u] = *(const f32x4*)(bb + g01 * 128 + (size_t)(2 * u + hi) * 4096);
            bvB[g01][u] = *(const f32x4*)(bb + g01 * 128 + (size_t)(8 + 2 * u + hi) * 4096);
        }

    for (int it = 0; it < N_ / MK; ++it) {
        int  cur  = it & 1;
        bool more = (it + 1 < N_ / MK);
        __syncthreads();   // drains vmcnt -> buf cur published; buf cur^1 free

        if (more) {        // async-stage next tile (fire-and-forget, drained at next barrier)
            int nxt = cur ^ 1;
            if (isK) {
                const bf16* ks = ksrc + (size_t)(it + 1) * MK * D_;
#pragma unroll
                for (int i = 0; i < 4; ++i) gll16(ks + (size_t)i * 8 * D_, &k_lds[nxt][wrow + i * 8][0], lane);
            } else {
                const bf16* vs = vsrc + (size_t)(it + 1) * 4096;
#pragma unroll
                for (int i = 0; i < 4; ++i) gll16(vs + (size_t)i * 128, &v_lds[nxt][wrow + i * 8][0], lane);
            }
        }

        // ================= half A: k-rows 0-31 of this tile =================
        {
            f32x16 s0 = {0,0,0,0,0,0,0,0,0,0,0,0,0,0,0,0};
            f32x16 s1 = {0,0,0,0,0,0,0,0,0,0,0,0,0,0,0,0};
            __builtin_amdgcn_s_setprio(1);
#pragma unroll
            for (int c = 0; c < 4; ++c) {
                int off = ((c << 4) | hi8) ^ key8;
                bf16x8 kb = *(const bf16x8*)(&k_lds[cur][q31][off]);   // one read, two MFMAs
                s0 = mfma32(kb, qA[c], s0);
                s1 = mfma32(kb, qB[c], s1);
            }
            __builtin_amdgcn_s_setprio(0);

            unsigned wa[2][4], wb[2][4];
#pragma unroll
            for (int g01 = 0; g01 < 2; ++g01) {
#pragma unroll
                for (int u = 0; u < 4; ++u) {
                    const f32x16& s = g01 ? s1 : s0;
                    f32x4 bvv = bvA[g01][u];
                    float p0 = __builtin_amdgcn_exp2f(__builtin_fmaf(-LOG2E, bvv[0], s[4*u+0]));
                    float p1 = __builtin_amdgcn_exp2f(__builtin_fmaf(-LOG2E, bvv[1], s[4*u+1]));
                    float p2 = __builtin_amdgcn_exp2f(__builtin_fmaf(-LOG2E, bvv[2], s[4*u+2]));
                    float p3 = __builtin_amdgcn_exp2f(__builtin_fmaf(-LOG2E, bvv[3], s[4*u+3]));
                    if (g01) l1 += (p0 + p1) + (p2 + p3); else l0 += (p0 + p1) + (p2 + p3);
                    wa[g01][u] = pk2(p0, p1);
                    wb[g01][u] = pk2(p2, p3);
                }
            }

            // refill half-A bias for next iter (bvA now dead; ~full-iter lead)
            if (more) {
#pragma unroll
                for (int g01 = 0; g01 < 2; ++g01)
#pragma unroll
                    for (int u = 0; u < 4; ++u)
                        bvA[g01][u] = *(const f32x4*)(bb + g01 * 128 + (size_t)((it + 1) * 16 + 2 * u + hi) * 4096);
            }

#pragma unroll
            for (int g01 = 0; g01 < 2; ++g01) {
                pl32swap(wa[g01][0], wa[g01][1], hi);
                pl32swap(wb[g01][0], wb[g01][1], hi);
                pl32swap(wa[g01][2], wa[g01][3], hi);
                pl32swap(wb[g01][2], wb[g01][3], hi);
            }

            __builtin_amdgcn_s_setprio(1);
#pragma unroll
            for (int c01 = 0; c01 < 2; ++c01) {        // kc = c01 (k-rows 0-31)
                int off = ((c01 << 4) | hi8) ^ key8;
                bf16x8 va0 = *(const bf16x8*)(&v_lds[cur][q31][off]);       // d 0-31
                bf16x8 va1 = *(const bf16x8*)(&v_lds[cur][32 + q31][off]);  // d 32-63
                i32x4 b0 = { (int)wa[0][2*c01], (int)wb[0][2*c01], (int)wa[0][2*c01+1], (int)wb[0][2*c01+1] };
                i32x4 b1 = { (int)wa[1][2*c01], (int)wb[1][2*c01], (int)wa[1][2*c01+1], (int)wb[1][2*c01+1] };
                bf16x8 pb0 = __builtin_bit_cast(bf16x8, b0);
                bf16x8 pb1 = __builtin_bit_cast(bf16x8, b1);
                acc00 = mfma32(va0, pb0, acc00);
                acc01 = mfma32(va1, pb0, acc01);
                acc10 = mfma32(va0, pb1, acc10);
                acc11 = mfma32(va1, pb1, acc11);
            }
            __builtin_amdgcn_s_setprio(0);
        }

        // ================= half B: k-rows 32-63 of this tile =================
        {
            f32x16 s0 = {0,0,0,0,0,0,0,0,0,0,0,0,0,0,0,0};
            f32x16 s1 = {0,0,0,0,0,0,0,0,0,0,0,0,0,0,0,0};
            __builtin_amdgcn_s_setprio(1);
#pragma unroll
            for (int c = 0; c < 4; ++c) {
                int off = ((c << 4) | hi8) ^ key8;
                bf16x8 kb = *(const bf16x8*)(&k_lds[cur][32 + q31][off]);
                s0 = mfma32(kb, qA[c], s0);
                s1 = mfma32(kb, qB[c], s1);
            }
            __builtin_amdgcn_s_setprio(0);

            unsigned wa[2][4], wb[2][4];
#pragma unroll
            for (int g01 = 0; g01 < 2; ++g01) {
#pragma unroll
                for (int u = 0; u < 4; ++u) {
                    const f32x16& s = g01 ? s1 : s0;
                    f32x4 bvv = bvB[g01][u];
                    float p0 = __builtin_amdgcn_exp2f(__builtin_fmaf(-LOG2E, bvv[0], s[4*u+0]));
                    float p1 = __builtin_amdgcn_exp2f(__builtin_fmaf(-LOG2E, bvv[1], s[4*u+1]));
                    float p2 = __builtin_amdgcn_exp2f(__builtin_fmaf(-LOG2E, bvv[2], s[4*u+2]));
                    float p3 = __builtin_amdgcn_exp2f(__builtin_fmaf(-LOG2E, bvv[3], s[4*u+3]));
                    if (g01) l1 += (p0 + p1) + (p2 + p3); else l0 += (p0 + p1) + (p2 + p3);
                    wa[g01][u] = pk2(p0, p1);
                    wb[g01][u] = pk2(p2, p3);
                }
            }

            // refill half-B bias for next iter
            if (more) {
#pragma unroll
                for (int g01 = 0; g01 < 2; ++g01)
#pragma unroll
                    for (int u = 0; u < 4; ++u)
                        bvB[g01][u] = *(const f32x4*)(bb + g01 * 128 + (size_t)((it + 1) * 16 + 8 + 2 * u + hi) * 4096);
            }

#pragma unroll
            for (int g01 = 0; g01 < 2; ++g01) {
                pl32swap(wa[g01][0], wa[g01][1], hi);
                pl32swap(wb[g01][0], wb[g01][1], hi);
                pl32swap(wa[g01][2], wa[g01][3], hi);
                pl32swap(wb[g01][2], wb[g01][3], hi);
            }

            __builtin_amdgcn_s_setprio(1);
#pragma unroll
            for (int c01 = 0; c01 < 2; ++c01) {        // kc = 2 + c01 (k-rows 32-63)
                int off = (((2 + c01) << 4) | hi8) ^ key8;
                bf16x8 va0 = *(const bf16x8*)(&v_lds[cur][q31][off]);
                bf16x8 va1 = *(const bf16x8*)(&v_lds[cur][32 + q31][off]);
                i32x4 b0 = { (int)wa[0][2*c01], (int)wb[0][2*c01], (int)wa[0][2*c01+1], (int)wb[0][2*c01+1] };
                i32x4 b1 = { (int)wa[1][2*c01], (int)wb[1][2*c01], (int)wa[1][2*c01+1], (int)wb[1][2*c01+1] };
                bf16x8 pb0 = __builtin_bit_cast(bf16x8, b0);
                bf16x8 pb1 = __builtin_bit_cast(bf16x8, b1);
                acc00 = mfma32(va0, pb0, acc00);
                acc01 = mfma32(va1, pb0, acc01);
                acc10 = mfma32(va0, pb1, acc10);
                acc11 = mfma32(va1, pb1, acc11);
            }
            __builtin_amdgcn_s_setprio(0);
        }
    }

    // ---- epilogue: l split across hi-halves only; one shfl per group ----
    l0 += __shfl_xor(l0, 32, 64);
    l1 += __shfl_xor(l1, 32, 64);
    float inv0 = 1.0f / l0, inv1 = 1.0f / l1;

#pragma unroll
    for (int g01 = 0; g01 < 2; ++g01) {
        float inv = g01 ? inv1 : inv0;
        float* ob = out + ((size_t)bgh * N_ + qbase + g01 * 32 + q31) * D_ + hi * 4;
#pragma unroll
        for (int td = 0; td < 2; ++td) {
            const f32x16& a = g01 ? (td ? acc11 : acc10) : (td ? acc01 : acc00);
#pragma unroll
            for (int u = 0; u < 4; ++u) {
                f32x4 o = { a[4*u+0] * inv, a[4*u+1] * inv, a[4*u+2] * inv, a[4*u+3] * inv };
                *(f32x4*)(ob + td * 32 + u * 8) = o;
            }
        }
    }
}

// ---------------------------------------------------------------------------
// Fallback (only if ws too small): naive fp32, one block per (bgh,n) row.
// ---------------------------------------------------------------------------
__global__ __launch_bounds__(256) void naive_kernel(
    const float* __restrict__ q, const float* __restrict__ k,
    const float* __restrict__ v, const float* __restrict__ bias,
    float* __restrict__ out)
{
    __shared__ float sc[N_];
    __shared__ float red[256];
    __shared__ float qrow[64];
    int n = blockIdx.x;
    int bgh = blockIdx.y;
    int bg = bgh >> 4, h = bgh & 15;
    int g = bg & (G_ - 1);
    int tid = threadIdx.x;
    const float* qr = q + ((size_t)(bg * N_ + n)) * 1024;
    if (tid < 64) qrow[tid] = qr[tid * 16 + h];
    __syncthreads();
    const float* bb = bias + (size_t)g * N_ * N_ + (size_t)n * N_;
    for (int m = tid; m < N_; m += 256) {
        const float* kr = k + ((size_t)(bg * N_ + m)) * 1024 + h;
        float dot = 0.f;
        for (int d = 0; d < 64; ++d) dot += qrow[d] * kr[d * 16];
        sc[m] = dot * 0.125f - bb[m];
    }
    __syncthreads();
    float mx = -INFINITY;
    for (int m = tid; m < N_; m += 256) mx = fmaxf(mx, sc[m]);
    red[tid] = mx; __syncthreads();
    for (int s = 128; s > 0; s >>= 1) {
        if (tid < s) red[tid] = fmaxf(red[tid], red[tid + s]);
        __syncthreads();
    }
    float M = red[0]; __syncthreads();
    float sum = 0.f;
    for (int m = tid; m < N_; m += 256) { float e = __expf(sc[m] - M); sc[m] = e; sum += e; }
    red[tid] = sum; __syncthreads();
    for (int s = 128; s > 0; s >>= 1) {
        if (tid < s) red[tid] += red[tid + s];
        __syncthreads();
    }
    float L = red[0]; __syncthreads();
    int d = tid & 63, quarter = tid >> 6;
    float acc = 0.f;
    const float* vb = v + (size_t)bg * N_ * 1024 + d * 16 + h;
    for (int m = quarter * 256; m < quarter * 256 + 256; ++m) acc += sc[m] * vb[(size_t)m * 1024];
    red[tid] = acc; __syncthreads();
    if (tid < 64) {
        float o = (red[tid] + red[tid + 64] + red[tid + 128] + red[tid + 192]) / L;
        out[((size_t)bgh * N_ + n) * 64 + d] = o;
    }
}

extern "C" void kernel_launch(void* const* d_in, const int* in_sizes, int n_in,
                              void* d_out, int out_size, void* d_ws, size_t ws_size,
                              hipStream_t stream) {
    const float* q    = (const float*)d_in[0];
    const float* k    = (const float*)d_in[1];
    const float* v    = (const float*)d_in[2];
    const float* bias = (const float*)d_in[3];
    float* out = (float*)d_out;

    const size_t elems = (size_t)BGH_ * N_ * D_;            // 8388608
    const size_t needA = 3 * elems * sizeof(bf16);          // 50.3 MB (qt,kt,vtT16)
    const size_t need  = needA + (size_t)G_ * N_ * N_ * 4;  // +16.8 MB biasX = 64 MiB

    if (ws_size >= need) {
        bf16* qt    = (bf16*)d_ws;
        bf16* ktb   = qt + elems;
        bf16* vtT16 = ktb + elems;
        float* biasX = (float*)((char*)d_ws + needA);
        transpose_fused<<<3 * 512 + 1024, 256, 0, stream>>>(q, k, v, bias, qt, ktb, vtT16, biasX);
        flash_kernel<<<dim3(512), 256, 0, stream>>>(qt, ktb, vtT16, biasX, out);
    } else {
        dim3 grid(N_, BGH_);
        naive_kernel<<<grid, 256, 0, stream>>>(q, k, v, bias, out);
    }
}

// Round 6
// 207.642 us; speedup vs baseline: 1.0858x; 1.0858x over previous
//
#include <hip/hip_runtime.h>
#include <hip/hip_bf16.h>
#include <math.h>

// Problem constants (GenNeuronStates): B=2,G=4,N=1024,H=16,dq=dv=64
#define B_ 2
#define G_ 4
#define N_ 1024
#define H_ 16
#define D_ 64
#define BG_ (B_*G_)
#define BGH_ (B_*G_*H_)
#define MK 64   // K/V tile rows per flash iteration
#define LOG2E 1.44269504f
#define QSCALE (0.125f * LOG2E)   // folded into Q during transpose

typedef __bf16 bf16;
typedef bf16 bf16x8 __attribute__((ext_vector_type(8)));
typedef bf16 bf16x2 __attribute__((ext_vector_type(2)));
typedef float f32x4 __attribute__((ext_vector_type(4)));
typedef float f32x16 __attribute__((ext_vector_type(16)));
typedef int i32x4 __attribute__((ext_vector_type(4)));
typedef unsigned u32x2 __attribute__((ext_vector_type(2)));

static __device__ __forceinline__ f32x16 mfma32(bf16x8 a, bf16x8 b, f32x16 c) {
    return __builtin_amdgcn_mfma_f32_32x32x16_bf16(a, b, c, 0, 0, 0);
}

// pack two f32 -> one dword of 2 bf16 (compiler emits v_cvt_pk_bf16_f32)
static __device__ __forceinline__ unsigned pk2(float a, float b) {
    bf16x2 t; t[0] = (bf16)a; t[1] = (bf16)b;
    return __builtin_bit_cast(unsigned, t);
}

// permlane32_swap: a' = {a.lo, b.lo}, b' = {a.hi, b.hi}  (halves = lanes 0-31 / 32-63)
static __device__ __forceinline__ void pl32swap(unsigned& a, unsigned& b, int hi) {
#if __has_builtin(__builtin_amdgcn_permlane32_swap)
    u32x2 r = __builtin_amdgcn_permlane32_swap(a, b, false, false);
    a = r[0]; b = r[1];
    (void)hi;
#else
    unsigned ax = (unsigned)__shfl_xor((int)a, 32, 64);
    unsigned bx = (unsigned)__shfl_xor((int)b, 32, 64);
    unsigned na = hi ? bx : a;
    unsigned nb = hi ? b : ax;
    a = na; b = nb;
#endif
}

// async global->LDS, 16B per lane; dest = wave-uniform base + lane*16 (m104)
static __device__ __forceinline__ void gll16(const void* gsrc, void* ldst, int lane) {
#if __has_builtin(__builtin_amdgcn_global_load_lds)
    (void)lane;
    __builtin_amdgcn_global_load_lds((const __attribute__((address_space(1))) void*)gsrc,
                                     (__attribute__((address_space(3))) void*)ldst, 16, 0, 0);
#else
    *(bf16x8*)((bf16*)ldst + lane * 8) = *(const bf16x8*)((const bf16*)gsrc);
#endif
}

// ---------------------------------------------------------------------------
// Fused prep pass.
//   bx < 1536 : Q/K/V transpose (V writes 16-chunked vtT16[bgh][n/16][d][16])
//   bx >= 1536: bias blocked-transpose biasX[g][m/4][q][4] (f32x4-granular)
// ---------------------------------------------------------------------------
#define HS 1160
#define NS 72

__global__ __launch_bounds__(256) void transpose_fused(
    const float* __restrict__ q, const float* __restrict__ k, const float* __restrict__ v,
    const float* __restrict__ bias,
    bf16* __restrict__ qt, bf16* __restrict__ ktb, bf16* __restrict__ vtT16,
    float* __restrict__ biasX)
{
    __shared__ __attribute__((aligned(16))) bf16 lds[16 * HS];  // 37.1 KB (reused by bias branch)
    int bx = blockIdx.x;
    int t = threadIdx.x;

    if (bx >= 3 * 512) {
        // ---- bias blocked transpose: biasX[((g*256+mb)*1024+q)*4+mo] = bias[g][q][4mb+mo]
        int idx = bx - 3 * 512;
        int gg  = idx >> 8;            // 0..3
        int tl  = idx & 255;
        int q0  = (tl >> 4) * 64;
        int m0  = (tl & 15) * 64;
        float* ldsF = (float*)lds;     // [64][68] f32, 17.4 KB

        int mi = t & 15, qr = t >> 4;
#pragma unroll
        for (int rr = 0; rr < 4; ++rr) {
            int row = qr + rr * 16;
            f32x4 val = *(const f32x4*)(bias + ((size_t)(gg * N_ + q0 + row) * N_ + m0 + 4 * mi));
            *(f32x4*)(&ldsF[row * 68 + 4 * mi]) = val;
        }
        __syncthreads();
        int qr2 = t & 63, mb0 = t >> 6;
#pragma unroll
        for (int kk = 0; kk < 4; ++kk) {
            int mbi = mb0 + kk * 4;    // 0..15
            f32x4 vv = *(const f32x4*)(&ldsF[qr2 * 68 + 4 * mbi]);
            *(f32x4*)(biasX + (((size_t)gg * 256 + m0 / 4 + mbi) * N_ + q0 + qr2) * 4) = vv;
        }
        return;
    }

    int tensor = bx >> 9;          // 512 blocks per tensor
    int rr = bx & 511;
    int bg = rr >> 6;
    int tile = rr & 63;
    int n0 = tile * 16;

    const float* src = (tensor == 0) ? q : (tensor == 1) ? k : v;
    float scale = (tensor == 0) ? QSCALE : 1.0f;
    const float* sb = src + (size_t)bg * N_ * 1024 + (size_t)n0 * 1024;

    int h0 = 4 * (t & 3);          // element j of the float4 has h = h0+j, same d
    int d  = t >> 2;
    int wbase = h0 * HS + d;
#pragma unroll 4
    for (int i = 0; i < 16; ++i) {
        float4 val = ((const float4*)(sb + (size_t)i * 1024))[t];
        bf16* p = &lds[wbase + i * NS];
        p[0]        = (bf16)(val.x * scale);
        p[HS]       = (bf16)(val.y * scale);
        p[2 * HS]   = (bf16)(val.z * scale);
        p[3 * HS]   = (bf16)(val.w * scale);
    }
    __syncthreads();

    if (tensor < 2) {
        bf16* dst = (tensor == 0) ? qt : ktb;
        int n  = (t >> 3) & 15;
        int db = t & 7;
        int hb = t >> 7;
#pragma unroll
        for (int i = 0; i < 8; ++i) {
            int h = 2 * i + hb;
            bf16x8 vv = *(const bf16x8*)(&lds[h * HS + n * NS + db * 8]);
            *(bf16x8*)(dst + (((size_t)(bg * H_ + h)) * N_ + n0 + n) * D_ + db * 8) = vv;
        }
    } else {
        // V -> vtT16[bgh][nchunk=tile][d][16]; lanes at consecutive d -> 2KB runs
        int dd = t & 63;
        int hb = t >> 6;           // 0..3
#pragma unroll
        for (int i = 0; i < 4; ++i) {
            int h = hb * 4 + i;
            bf16x8 v0, v1;
#pragma unroll
            for (int jj = 0; jj < 8; ++jj) v0[jj] = lds[h * HS + jj * NS + dd];
#pragma unroll
            for (int jj = 0; jj < 8; ++jj) v1[jj] = lds[h * HS + (8 + jj) * NS + dd];
            bf16* dst = vtT16 + (((size_t)(bg * H_ + h) * 64 + tile) * D_ + dd) * 16;
            *(bf16x8*)dst       = v0;
            *(bf16x8*)(dst + 8) = v1;
        }
    }
}

// ---------------------------------------------------------------------------
// Flash v11 = v10 with the spill fixed (v10: WRITE_SIZE 58MB = ~26MB scratch).
// Bias register buffer halved 64->32 VGPR: ONE bv[2][4], refilled twice per
// iter at point-of-death (after half-A consumption -> loads half-B bias of
// the SAME iter, unconditional; after half-B -> next iter's half-A). Lead
// ~600-900cy per refill vs ~200cy L2 hit (bias L2-resident via XCD swizzle).
// Rest = v10: 2x LDS-read reuse (each wave owns 64 q-cols, K/V frag reads
// feed both groups; 16 b128 reads -> 32 MFMAs/wave-iter), two 32-row halves
// per K-tile, block = 256 q-rows, grid 512, gll16 staging, 1 barrier/iter.
// ---------------------------------------------------------------------------
__global__ __launch_bounds__(256, 2) void flash_kernel(
    const bf16* __restrict__ qt, const bf16* __restrict__ kt, const bf16* __restrict__ vtT16,
    const float* __restrict__ biasX, float* __restrict__ out)
{
    __shared__ __attribute__((aligned(16))) bf16 k_lds[2][MK][D_];  // [buf][m][d] linear
    __shared__ __attribute__((aligned(16))) bf16 v_lds[2][D_][MK];  // [buf][d][m] linear

    int tid  = threadIdx.x;
    int w    = tid >> 6;
    int lane = tid & 63;
    int hi   = lane >> 5;
    int q31  = lane & 31;
    int key8 = (q31 & 7) << 3;     // elem-XOR key for frag reads (8-elem granule)
    int hi8  = hi << 3;

    // XCD-bijective swizzle: 512 blocks; each XCD owns one (b,g) = 16 bgh x 4 qtiles
    int wg   = blockIdx.x;
    int xcd  = wg & 7;
    int slot = wg >> 3;            // 0..63
    int bgh  = xcd * 16 + (slot >> 2);
    int n0   = (slot & 3) * 256;
    int g    = (bgh >> 4) & (G_ - 1);   // bgh = (b*G+g)*H + h

    int qbase = n0 + w * 64;

    // Q B-frags, both groups (loop-invariant): 8 x bf16x8 = 32 VGPR
    const bf16* qb_base = qt + ((size_t)bgh * N_ + qbase + q31) * D_ + hi * 8;
    bf16x8 qA[4], qB[4];
#pragma unroll
    for (int c = 0; c < 4; ++c) {
        qA[c] = *(const bf16x8*)(qb_base + c * 16);
        qB[c] = *(const bf16x8*)(qb_base + 32 * D_ + c * 16);
    }

    f32x16 acc00 = {0,0,0,0,0,0,0,0,0,0,0,0,0,0,0,0};  // g0, d 0-31
    f32x16 acc01 = {0,0,0,0,0,0,0,0,0,0,0,0,0,0,0,0};  // g0, d 32-63
    f32x16 acc10 = {0,0,0,0,0,0,0,0,0,0,0,0,0,0,0,0};  // g1, d 0-31
    f32x16 acc11 = {0,0,0,0,0,0,0,0,0,0,0,0,0,0,0,0};  // g1, d 32-63
    float l0 = 0.f, l1 = 0.f;

    // ---- staging geometry: waves 0,1 stage K rows wrow..wrow+31; waves 2,3 stage V
    int rloc = lane >> 3;              // 0..7
    int c16  = lane & 7;               // 16B chunk within 128B row
    int csw  = c16 ^ rloc;             // source chunk (row&7 == rloc for all instrs)
    bool isK = (w < 2);
    int wrow = (w & 1) * 32;
    const bf16* ksrc = kt + (size_t)bgh * N_ * D_ + (size_t)(wrow + rloc) * D_ + csw * 8;
    const bf16* vsrc = vtT16 + (((size_t)bgh * 64 + (csw >> 1)) * D_ + (wrow + rloc)) * 16 + (csw & 1) * 8;

    // ---- bias: lane's q-col in biasX; quad (mb) at mb*4096 floats; group1 at +128
    const float* bb = biasX + (size_t)g * (256u * 4096) + (size_t)(qbase + q31) * 4;

    // ---- prologue: stage tile 0 + bias half-A of iter 0 ----
    if (isK) {
#pragma unroll
        for (int i = 0; i < 4; ++i) gll16(ksrc + (size_t)i * 8 * D_, &k_lds[0][wrow + i * 8][0], lane);
    } else {
#pragma unroll
        for (int i = 0; i < 4; ++i) gll16(vsrc + (size_t)i * 128, &v_lds[0][wrow + i * 8][0], lane);
    }
    f32x4 bv[2][4];   // SINGLE bias buffer (32 VGPR) — refilled twice per iter
#pragma unroll
    for (int g01 = 0; g01 < 2; ++g01)
#pragma unroll
        for (int u = 0; u < 4; ++u)
            bv[g01][u] = *(const f32x4*)(bb + g01 * 128 + (size_t)(2 * u + hi) * 4096);

    for (int it = 0; it < N_ / MK; ++it) {
        int  cur  = it & 1;
        bool more = (it + 1 < N_ / MK);
        __syncthreads();   // drains vmcnt -> buf cur published; buf cur^1 free

        if (more) {        // async-stage next tile (fire-and-forget, drained at next barrier)
            int nxt = cur ^ 1;
            if (isK) {
                const bf16* ks = ksrc + (size_t)(it + 1) * MK * D_;
#pragma unroll
                for (int i = 0; i < 4; ++i) gll16(ks + (size_t)i * 8 * D_, &k_lds[nxt][wrow + i * 8][0], lane);
            } else {
                const bf16* vs = vsrc + (size_t)(it + 1) * 4096;
#pragma unroll
                for (int i = 0; i < 4; ++i) gll16(vs + (size_t)i * 128, &v_lds[nxt][wrow + i * 8][0], lane);
            }
        }

        // ================= half A: k-rows 0-31 of this tile =================
        {
            f32x16 s0 = {0,0,0,0,0,0,0,0,0,0,0,0,0,0,0,0};
            f32x16 s1 = {0,0,0,0,0,0,0,0,0,0,0,0,0,0,0,0};
            __builtin_amdgcn_s_setprio(1);
#pragma unroll
            for (int c = 0; c < 4; ++c) {
                int off = ((c << 4) | hi8) ^ key8;
                bf16x8 kb = *(const bf16x8*)(&k_lds[cur][q31][off]);   // one read, two MFMAs
                s0 = mfma32(kb, qA[c], s0);
                s1 = mfma32(kb, qB[c], s1);
            }
            __builtin_amdgcn_s_setprio(0);

            unsigned wa[2][4], wb[2][4];
#pragma unroll
            for (int g01 = 0; g01 < 2; ++g01) {
#pragma unroll
                for (int u = 0; u < 4; ++u) {
                    const f32x16& s = g01 ? s1 : s0;
                    f32x4 bvv = bv[g01][u];
                    float p0 = __builtin_amdgcn_exp2f(__builtin_fmaf(-LOG2E, bvv[0], s[4*u+0]));
                    float p1 = __builtin_amdgcn_exp2f(__builtin_fmaf(-LOG2E, bvv[1], s[4*u+1]));
                    float p2 = __builtin_amdgcn_exp2f(__builtin_fmaf(-LOG2E, bvv[2], s[4*u+2]));
                    float p3 = __builtin_amdgcn_exp2f(__builtin_fmaf(-LOG2E, bvv[3], s[4*u+3]));
                    if (g01) l1 += (p0 + p1) + (p2 + p3); else l0 += (p0 + p1) + (p2 + p3);
                    wa[g01][u] = pk2(p0, p1);
                    wb[g01][u] = pk2(p2, p3);
                }
            }

            // refill bv with half-B bias of THIS iter (unconditional; bv now dead)
#pragma unroll
            for (int g01 = 0; g01 < 2; ++g01)
#pragma unroll
                for (int u = 0; u < 4; ++u)
                    bv[g01][u] = *(const f32x4*)(bb + g01 * 128 + (size_t)(it * 16 + 8 + 2 * u + hi) * 4096);

#pragma unroll
            for (int g01 = 0; g01 < 2; ++g01) {
                pl32swap(wa[g01][0], wa[g01][1], hi);
                pl32swap(wb[g01][0], wb[g01][1], hi);
                pl32swap(wa[g01][2], wa[g01][3], hi);
                pl32swap(wb[g01][2], wb[g01][3], hi);
            }

            __builtin_amdgcn_s_setprio(1);
#pragma unroll
            for (int c01 = 0; c01 < 2; ++c01) {        // kc = c01 (k-rows 0-31)
                int off = ((c01 << 4) | hi8) ^ key8;
                bf16x8 va0 = *(const bf16x8*)(&v_lds[cur][q31][off]);       // d 0-31
                bf16x8 va1 = *(const bf16x8*)(&v_lds[cur][32 + q31][off]);  // d 32-63
                i32x4 b0 = { (int)wa[0][2*c01], (int)wb[0][2*c01], (int)wa[0][2*c01+1], (int)wb[0][2*c01+1] };
                i32x4 b1 = { (int)wa[1][2*c01], (int)wb[1][2*c01], (int)wa[1][2*c01+1], (int)wb[1][2*c01+1] };
                bf16x8 pb0 = __builtin_bit_cast(bf16x8, b0);
                bf16x8 pb1 = __builtin_bit_cast(bf16x8, b1);
                acc00 = mfma32(va0, pb0, acc00);
                acc01 = mfma32(va1, pb0, acc01);
                acc10 = mfma32(va0, pb1, acc10);
                acc11 = mfma32(va1, pb1, acc11);
            }
            __builtin_amdgcn_s_setprio(0);
        }

        // ================= half B: k-rows 32-63 of this tile =================
        {
            f32x16 s0 = {0,0,0,0,0,0,0,0,0,0,0,0,0,0,0,0};
            f32x16 s1 = {0,0,0,0,0,0,0,0,0,0,0,0,0,0,0,0};
            __builtin_amdgcn_s_setprio(1);
#pragma unroll
            for (int c = 0; c < 4; ++c) {
                int off = ((c << 4) | hi8) ^ key8;
                bf16x8 kb = *(const bf16x8*)(&k_lds[cur][32 + q31][off]);
                s0 = mfma32(kb, qA[c], s0);
                s1 = mfma32(kb, qB[c], s1);
            }
            __builtin_amdgcn_s_setprio(0);

            unsigned wa[2][4], wb[2][4];
#pragma unroll
            for (int g01 = 0; g01 < 2; ++g01) {
#pragma unroll
                for (int u = 0; u < 4; ++u) {
                    const f32x16& s = g01 ? s1 : s0;
                    f32x4 bvv = bv[g01][u];
                    float p0 = __builtin_amdgcn_exp2f(__builtin_fmaf(-LOG2E, bvv[0], s[4*u+0]));
                    float p1 = __builtin_amdgcn_exp2f(__builtin_fmaf(-LOG2E, bvv[1], s[4*u+1]));
                    float p2 = __builtin_amdgcn_exp2f(__builtin_fmaf(-LOG2E, bvv[2], s[4*u+2]));
                    float p3 = __builtin_amdgcn_exp2f(__builtin_fmaf(-LOG2E, bvv[3], s[4*u+3]));
                    if (g01) l1 += (p0 + p1) + (p2 + p3); else l0 += (p0 + p1) + (p2 + p3);
                    wa[g01][u] = pk2(p0, p1);
                    wb[g01][u] = pk2(p2, p3);
                }
            }

            // refill bv with next-iter half-A bias
            if (more) {
#pragma unroll
                for (int g01 = 0; g01 < 2; ++g01)
#pragma unroll
                    for (int u = 0; u < 4; ++u)
                        bv[g01][u] = *(const f32x4*)(bb + g01 * 128 + (size_t)((it + 1) * 16 + 2 * u + hi) * 4096);
            }

#pragma unroll
            for (int g01 = 0; g01 < 2; ++g01) {
                pl32swap(wa[g01][0], wa[g01][1], hi);
                pl32swap(wb[g01][0], wb[g01][1], hi);
                pl32swap(wa[g01][2], wa[g01][3], hi);
                pl32swap(wb[g01][2], wb[g01][3], hi);
            }

            __builtin_amdgcn_s_setprio(1);
#pragma unroll
            for (int c01 = 0; c01 < 2; ++c01) {        // kc = 2 + c01 (k-rows 32-63)
                int off = (((2 + c01) << 4) | hi8) ^ key8;
                bf16x8 va0 = *(const bf16x8*)(&v_lds[cur][q31][off]);
                bf16x8 va1 = *(const bf16x8*)(&v_lds[cur][32 + q31][off]);
                i32x4 b0 = { (int)wa[0][2*c01], (int)wb[0][2*c01], (int)wa[0][2*c01+1], (int)wb[0][2*c01+1] };
                i32x4 b1 = { (int)wa[1][2*c01], (int)wb[1][2*c01], (int)wa[1][2*c01+1], (int)wb[1][2*c01+1] };
                bf16x8 pb0 = __builtin_bit_cast(bf16x8, b0);
                bf16x8 pb1 = __builtin_bit_cast(bf16x8, b1);
                acc00 = mfma32(va0, pb0, acc00);
                acc01 = mfma32(va1, pb0, acc01);
                acc10 = mfma32(va0, pb1, acc10);
                acc11 = mfma32(va1, pb1, acc11);
            }
            __builtin_amdgcn_s_setprio(0);
        }
    }

    // ---- epilogue: l split across hi-halves only; one shfl per group ----
    l0 += __shfl_xor(l0, 32, 64);
    l1 += __shfl_xor(l1, 32, 64);
    float inv0 = 1.0f / l0, inv1 = 1.0f / l1;

#pragma unroll
    for (int g01 = 0; g01 < 2; ++g01) {
        float inv = g01 ? inv1 : inv0;
        float* ob = out + ((size_t)bgh * N_ + qbase + g01 * 32 + q31) * D_ + hi * 4;
#pragma unroll
        for (int td = 0; td < 2; ++td) {
            const f32x16& a = g01 ? (td ? acc11 : acc10) : (td ? acc01 : acc00);
#pragma unroll
            for (int u = 0; u < 4; ++u) {
                f32x4 o = { a[4*u+0] * inv, a[4*u+1] * inv, a[4*u+2] * inv, a[4*u+3] * inv };
                *(f32x4*)(ob + td * 32 + u * 8) = o;
            }
        }
    }
}

// ---------------------------------------------------------------------------
// Fallback (only if ws too small): naive fp32, one block per (bgh,n) row.
// ---------------------------------------------------------------------------
__global__ __launch_bounds__(256) void naive_kernel(
    const float* __restrict__ q, const float* __restrict__ k,
    const float* __restrict__ v, const float* __restrict__ bias,
    float* __restrict__ out)
{
    __shared__ float sc[N_];
    __shared__ float red[256];
    __shared__ float qrow[64];
    int n = blockIdx.x;
    int bgh = blockIdx.y;
    int bg = bgh >> 4, h = bgh & 15;
    int g = bg & (G_ - 1);
    int tid = threadIdx.x;
    const float* qr = q + ((size_t)(bg * N_ + n)) * 1024;
    if (tid < 64) qrow[tid] = qr[tid * 16 + h];
    __syncthreads();
    const float* bb = bias + (size_t)g * N_ * N_ + (size_t)n * N_;
    for (int m = tid; m < N_; m += 256) {
        const float* kr = k + ((size_t)(bg * N_ + m)) * 1024 + h;
        float dot = 0.f;
        for (int d = 0; d < 64; ++d) dot += qrow[d] * kr[d * 16];
        sc[m] = dot * 0.125f - bb[m];
    }
    __syncthreads();
    float mx = -INFINITY;
    for (int m = tid; m < N_; m += 256) mx = fmaxf(mx, sc[m]);
    red[tid] = mx; __syncthreads();
    for (int s = 128; s > 0; s >>= 1) {
        if (tid < s) red[tid] = fmaxf(red[tid], red[tid + s]);
        __syncthreads();
    }
    float M = red[0]; __syncthreads();
    float sum = 0.f;
    for (int m = tid; m < N_; m += 256) { float e = __expf(sc[m] - M); sc[m] = e; sum += e; }
    red[tid] = sum; __syncthreads();
    for (int s = 128; s > 0; s >>= 1) {
        if (tid < s) red[tid] += red[tid + s];
        __syncthreads();
    }
    float L = red[0]; __syncthreads();
    int d = tid & 63, quarter = tid >> 6;
    float acc = 0.f;
    const float* vb = v + (size_t)bg * N_ * 1024 + d * 16 + h;
    for (int m = quarter * 256; m < quarter * 256 + 256; ++m) acc += sc[m] * vb[(size_t)m * 1024];
    red[tid] = acc; __syncthreads();
    if (tid < 64) {
        float o = (red[tid] + red[tid + 64] + red[tid + 128] + red[tid + 192]) / L;
        out[((size_t)bgh * N_ + n) * 64 + d] = o;
    }
}

extern "C" void kernel_launch(void* const* d_in, const int* in_sizes, int n_in,
                              void* d_out, int out_size, void* d_ws, size_t ws_size,
                              hipStream_t stream) {
    const float* q    = (const float*)d_in[0];
    const float* k    = (const float*)d_in[1];
    const float* v    = (const float*)d_in[2];
    const float* bias = (const float*)d_in[3];
    float* out = (float*)d_out;

    const size_t elems = (size_t)BGH_ * N_ * D_;            // 8388608
    const size_t needA = 3 * elems * sizeof(bf16);          // 50.3 MB (qt,kt,vtT16)
    const size_t need  = needA + (size_t)G_ * N_ * N_ * 4;  // +16.8 MB biasX = 64 MiB

    if (ws_size >= need) {
        bf16* qt    = (bf16*)d_ws;
        bf16* ktb   = qt + elems;
        bf16* vtT16 = ktb + elems;
        float* biasX = (float*)((char*)d_ws + needA);
        transpose_fused<<<3 * 512 + 1024, 256, 0, stream>>>(q, k, v, bias, qt, ktb, vtT16, biasX);
        flash_kernel<<<dim3(512), 256, 0, stream>>>(qt, ktb, vtT16, biasX, out);
    } else {
        dim3 grid(N_, BGH_);
        naive_kernel<<<grid, 256, 0, stream>>>(q, k, v, bias, out);
    }
}